// Round 2
// baseline (24728.957 us; speedup 1.0000x reference)
//
#include <hip/hip_runtime.h>
#include <math.h>

#define N_PTS 32768
#define M_SEL 8192
#define K_NBR 64
#define F_IN  64
#define H_MID 128
#define C_OUT 128
#define NCELL 512   // 8x8x8 grid
#define CAP   192   // per-centroid candidate cap (Poisson(70) tail ~ 0)

// ---------- helpers ----------

__device__ __forceinline__ int clamp8(int v) { return v < 0 ? 0 : (v > 7 ? 7 : v); }

__device__ __forceinline__ int cell_of(float px, float py, float pz) {
    int ix = clamp8((int)(px * 8.0f));
    int iy = clamp8((int)(py * 8.0f));
    int iz = clamp8((int)(pz * 8.0f));
    return (iz * 8 + iy) * 8 + ix;
}

// Bit-exact replica of numpy: ((dx*dx + dy*dy) + dz*dz), rn, no fma.
__device__ __forceinline__ float d2_exact(float ax, float ay, float az,
                                          float bx, float by, float bz) {
#pragma clang fp contract(off)
    float dx = ax - bx, dy = ay - by, dz = az - bz;
    return (dx * dx + dy * dy) + dz * dz;
}

// ---------- binning ----------

__global__ void bin_count_kernel(const float* __restrict__ pos, int* __restrict__ cnt) {
    int i = blockIdx.x * blockDim.x + threadIdx.x;
    if (i < N_PTS) {
        atomicAdd(&cnt[cell_of(pos[3*i], pos[3*i+1], pos[3*i+2])], 1);
    }
}

__global__ void scan_kernel(const int* __restrict__ cnt, int* __restrict__ start,
                            int* __restrict__ fill) {
    __shared__ int s[NCELL];
    int t = threadIdx.x;
    int v = cnt[t];
    s[t] = v;
    __syncthreads();
    for (int off = 1; off < NCELL; off <<= 1) {
        int add = (t >= off) ? s[t - off] : 0;
        __syncthreads();
        s[t] += add;
        __syncthreads();
    }
    int ex = s[t] - v;           // exclusive scan
    start[t] = ex;
    fill[t]  = ex;
    if (t == NCELL - 1) start[NCELL] = s[t];
}

__global__ void scatter_kernel(const float* __restrict__ pos, int* __restrict__ fill,
                               float* __restrict__ sx, float* __restrict__ sy,
                               float* __restrict__ sz, int* __restrict__ orig) {
    int i = blockIdx.x * blockDim.x + threadIdx.x;
    if (i < N_PTS) {
        float px = pos[3*i], py = pos[3*i+1], pz = pos[3*i+2];
        int c = cell_of(px, py, pz);
        int slot = atomicAdd(&fill[c], 1);
        sx[slot] = px; sy[slot] = py; sz[slot] = pz;
        orig[slot] = i;
    }
}

// ---------- FPS (single workgroup, cell-pruned) ----------

__global__ __launch_bounds__(1024) void fps_kernel(
        const float* __restrict__ pos,
        const float* __restrict__ sx, const float* __restrict__ sy,
        const float* __restrict__ sz, const int* __restrict__ orig,
        const int* __restrict__ cstart,
        float* __restrict__ mind, int* __restrict__ sel) {
    __shared__ float s_cmax[NCELL];
    __shared__ int   s_cbest[NCELL];
    __shared__ int   s_csidx[NCELL];
    __shared__ int   s_flag[NCELL];
    __shared__ int   s_nflag;
    __shared__ float s_px, s_py, s_pz;
    __shared__ float s_pval[16];
    __shared__ int   s_pbest[16];
    __shared__ int   s_psidx[16];

    const int tid  = threadIdx.x;
    const int lane = tid & 63;
    const int wid  = tid >> 6;
    const float NEG = -INFINITY;

    // init: mind = +inf, cells = empty, flag all nonempty cells, p = pos[0]
    for (int i = tid; i < N_PTS; i += 1024) mind[i] = INFINITY;
    if (tid < NCELL) { s_cmax[tid] = NEG; s_cbest[tid] = 0x7fffffff; s_csidx[tid] = 0; }
    if (tid == 0) {
        s_nflag = 0;
        s_px = pos[0]; s_py = pos[1]; s_pz = pos[2];
        sel[0] = 0;
    }
    __syncthreads();
    if (tid < NCELL) {
        if (cstart[tid + 1] > cstart[tid]) {
            int slot = atomicAdd(&s_nflag, 1);
            s_flag[slot] = tid;
        }
    }
    __threadfence_block();
    __syncthreads();

    for (int m = 1; m < M_SEL; ++m) {
        // --- update flagged cells vs current point; recompute their (max, argbest) ---
        float px = s_px, py = s_py, pz = s_pz;
        int nf = s_nflag;
        for (int f = wid; f < nf; f += 16) {
            int c  = s_flag[f];
            int cs = cstart[c], ce = cstart[c + 1];
            float bv = NEG; int bo = 0x7fffffff; int bs = 0;
            for (int j = cs + lane; j < ce; j += 64) {
                float d2  = d2_exact(sx[j], sy[j], sz[j], px, py, pz);
                float old = mind[j];
                float nv  = d2 < old ? d2 : old;
                if (nv < old) mind[j] = nv;
                int o = orig[j];
                if (nv > bv || (nv == bv && o < bo)) { bv = nv; bo = o; bs = j; }
            }
            for (int off = 32; off > 0; off >>= 1) {
                float ov = __shfl_down(bv, off);
                int   oo = __shfl_down(bo, off);
                int   os = __shfl_down(bs, off);
                if (ov > bv || (ov == bv && oo < bo)) { bv = ov; bo = oo; bs = os; }
            }
            if (lane == 0) { s_cmax[c] = bv; s_cbest[c] = bo; s_csidx[c] = bs; }
        }
        __threadfence_block();
        __syncthreads();

        // --- argmax over 512 cells (first-orig-index tie-break) ---
        if (wid < 8) {
            float bv = s_cmax[tid];
            int   bo = s_cbest[tid];
            int   bs = s_csidx[tid];
            for (int off = 32; off > 0; off >>= 1) {
                float ov = __shfl_down(bv, off);
                int   oo = __shfl_down(bo, off);
                int   os = __shfl_down(bs, off);
                if (ov > bv || (ov == bv && oo < bo)) { bv = ov; bo = oo; bs = os; }
            }
            if (lane == 0) { s_pval[wid] = bv; s_pbest[wid] = bo; s_psidx[wid] = bs; }
        }
        if (tid == 1023) s_nflag = 0;
        __syncthreads();
        if (wid == 0) {
            float bv = (lane < 8) ? s_pval[lane]  : NEG;
            int   bo = (lane < 8) ? s_pbest[lane] : 0x7fffffff;
            int   bs = (lane < 8) ? s_psidx[lane] : 0;
            for (int off = 4; off > 0; off >>= 1) {
                float ov = __shfl_down(bv, off);
                int   oo = __shfl_down(bo, off);
                int   os = __shfl_down(bs, off);
                if (ov > bv || (ov == bv && oo < bo)) { bv = ov; bo = oo; bs = os; }
            }
            if (lane == 0) {
                sel[m] = bo;
                s_px = sx[bs]; s_py = sy[bs]; s_pz = sz[bs];
            }
        }
        __syncthreads();

        // --- flag cells for next update: bbox lower bound < cell max (safe margin) ---
        if (tid < NCELL) {
            int c = tid;
            float cm = s_cmax[c];
            float lox = (float)(c & 7)        * 0.125f;
            float loy = (float)((c >> 3) & 7) * 0.125f;
            float loz = (float)(c >> 6)       * 0.125f;
            float qx = s_px, qy = s_py, qz = s_pz;
            float dx = fmaxf(fmaxf(lox - qx, qx - (lox + 0.125f)), 0.0f);
            float dy = fmaxf(fmaxf(loy - qy, qy - (loy + 0.125f)), 0.0f);
            float dz = fmaxf(fmaxf(loz - qz, qz - (loz + 0.125f)), 0.0f);
            float lb2 = dx * dx + dy * dy + dz * dz;
            if (lb2 * 0.999f < cm) {           // conservative: flags strictly more
                int slot = atomicAdd(&s_nflag, 1);
                s_flag[slot] = c;
            }
        }
        __syncthreads();
    }
}

// ---------- ball query: up-to-64 nearest in-radius (one wave / centroid) ----------

__global__ __launch_bounds__(256) void ballq_kernel(
        const float* __restrict__ pos,
        const float* __restrict__ sx, const float* __restrict__ sy,
        const float* __restrict__ sz, const int* __restrict__ orig,
        const int* __restrict__ cstart, const int* __restrict__ sel,
        int* __restrict__ nbr, int* __restrict__ ncnt) {
    __shared__ float s_d2[4][CAP];
    __shared__ int   s_o[4][CAP];
    __shared__ int   s_cnt[4];

    const int wid  = threadIdx.x >> 6;
    const int lane = threadIdx.x & 63;
    const int m = blockIdx.x * 4 + wid;

    if (lane == 0) s_cnt[wid] = 0;
    __syncthreads();

    int sidx = sel[m];
    float cx = pos[3*sidx], cy = pos[3*sidx+1], cz = pos[3*sidx+2];
    int ix = clamp8((int)(cx * 8.0f));
    int iy = clamp8((int)(cy * 8.0f));
    int iz = clamp8((int)(cz * 8.0f));
    const float r2 = (float)(0.08 * 0.08);

    for (int dz = -1; dz <= 1; ++dz) {
        int z = iz + dz; if (z < 0 || z > 7) continue;
        for (int dy = -1; dy <= 1; ++dy) {
            int y = iy + dy; if (y < 0 || y > 7) continue;
            for (int dx = -1; dx <= 1; ++dx) {
                int xq = ix + dx; if (xq < 0 || xq > 7) continue;
                int c = (z * 8 + y) * 8 + xq;
                int cs = cstart[c], ce = cstart[c + 1];
                for (int j = cs + lane; j < ce; j += 64) {
                    float d2 = d2_exact(cx, cy, cz, sx[j], sy[j], sz[j]);
                    if (d2 <= r2) {
                        int slot = atomicAdd(&s_cnt[wid], 1);
                        if (slot < CAP) { s_d2[wid][slot] = d2; s_o[wid][slot] = orig[j]; }
                    }
                }
            }
        }
    }
    __syncthreads();

    int cnt = s_cnt[wid];
    if (cnt > CAP) cnt = CAP;
    if (cnt <= K_NBR) {
        if (lane < cnt) nbr[m * K_NBR + lane] = s_o[wid][lane];
        if (lane == 0) ncnt[m] = cnt;
    } else {
        // exact (d2, orig-index) lexicographic rank -> keep 64 nearest (matches top_k)
        for (int i = lane; i < cnt; i += 64) {
            float d2 = s_d2[wid][i];
            int   o  = s_o[wid][i];
            int rank = 0;
            for (int j = 0; j < cnt; ++j) {
                float dj = s_d2[wid][j];
                int   oj = s_o[wid][j];
                rank += (dj < d2 || (dj == d2 && oj < o)) ? 1 : 0;
            }
            if (rank < K_NBR) nbr[m * K_NBR + rank] = o;
        }
        if (lane == 0) ncnt[m] = K_NBR;
    }
}

// ---------- PointConv MLP + masked max-pool (fp32, one block / centroid) ----------

__global__ __launch_bounds__(256) void mlp_kernel(
        const float* __restrict__ x, const float* __restrict__ pos,
        const float* __restrict__ W1, const float* __restrict__ b1,
        const float* __restrict__ W2, const float* __restrict__ b2,
        const int* __restrict__ sel, const int* __restrict__ nbr,
        const int* __restrict__ ncnt, float* __restrict__ out) {
    __shared__ __align__(16) float feat[64][68];   // 67 used + pad
    __shared__ __align__(16) float h[64][H_MID];
    __shared__ float part[2][H_MID];

    const int m = blockIdx.x;
    const int tid = threadIdx.x;
    const int cnt = ncnt[m];
    const int s = sel[m];
    float cx = pos[3*s], cy = pos[3*s+1], cz = pos[3*s+2];

    for (int i = tid; i < 64 * 68; i += 256) ((float*)feat)[i] = 0.0f;
    __syncthreads();

    for (int i = tid; i < cnt * F_IN; i += 256) {
        int k = i >> 6, f = i & 63;
        int j = nbr[m * K_NBR + k];
        feat[k][f] = x[(size_t)j * F_IN + f];
    }
    if (tid < 64 && tid < cnt) {
        int j = nbr[m * K_NBR + tid];
        // plain subtraction: no contraction hazard (no mul+add to fuse)
        feat[tid][64] = pos[3*j]     - cx;
        feat[tid][65] = pos[3*j + 1] - cy;
        feat[tid][66] = pos[3*j + 2] - cz;
    }
    __syncthreads();

    const int c = tid & 127;
    const int half = tid >> 7;

    // layer 1: h[k][c] = relu(feat[k][:] . W1[:,c] + b1[c])
    for (int k = half; k < 64; k += 2) {
        float acc = b1[c];
        const float4* fr = (const float4*)&feat[k][0];
#pragma unroll
        for (int f4 = 0; f4 < 16; ++f4) {
            float4 fv = fr[f4];
            int fb = f4 * 4;
            acc = fmaf(fv.x, W1[(fb    ) * H_MID + c], acc);
            acc = fmaf(fv.y, W1[(fb + 1) * H_MID + c], acc);
            acc = fmaf(fv.z, W1[(fb + 2) * H_MID + c], acc);
            acc = fmaf(fv.w, W1[(fb + 3) * H_MID + c], acc);
        }
        acc = fmaf(feat[k][64], W1[64 * H_MID + c], acc);
        acc = fmaf(feat[k][65], W1[65 * H_MID + c], acc);
        acc = fmaf(feat[k][66], W1[66 * H_MID + c], acc);
        h[k][c] = fmaxf(acc, 0.0f);
    }
    __syncthreads();

    // layer 2 + max over valid k
    float best = -INFINITY;
    for (int k = half; k < cnt; k += 2) {
        float acc = 0.0f;
        const float4* hr = (const float4*)&h[k][0];
#pragma unroll
        for (int q = 0; q < 32; ++q) {
            float4 hv = hr[q];
            int hb = q * 4;
            acc = fmaf(hv.x, W2[(hb    ) * C_OUT + c], acc);
            acc = fmaf(hv.y, W2[(hb + 1) * C_OUT + c], acc);
            acc = fmaf(hv.z, W2[(hb + 2) * C_OUT + c], acc);
            acc = fmaf(hv.w, W2[(hb + 3) * C_OUT + c], acc);
        }
        best = fmaxf(best, acc);
    }
    part[half][c] = best;
    __syncthreads();
    if (tid < 128) {
        out[(size_t)m * C_OUT + tid] = fmaxf(part[0][tid], part[1][tid]) + b2[tid];
    }
}

// ---------- outputs 2 & 3 ----------

__global__ void tail_kernel(const float* __restrict__ pos, const int* __restrict__ sel,
                            float* __restrict__ out_selpos, float* __restrict__ out_batch) {
    int i = blockIdx.x * blockDim.x + threadIdx.x;
    if (i < M_SEL) {
        int s = sel[i];
        out_selpos[3*i]     = pos[3*s];
        out_selpos[3*i + 1] = pos[3*s + 1];
        out_selpos[3*i + 2] = pos[3*s + 2];
        out_batch[i] = 0.0f;
    }
}

// ---------- launch ----------

extern "C" void kernel_launch(void* const* d_in, const int* in_sizes, int n_in,
                              void* d_out, int out_size, void* d_ws, size_t ws_size,
                              hipStream_t stream) {
    const float* x   = (const float*)d_in[0];
    const float* pos = (const float*)d_in[1];
    // d_in[2] = batch (int64, all zeros) — unused
    const float* W1 = (const float*)d_in[3];
    const float* b1 = (const float*)d_in[4];
    const float* W2 = (const float*)d_in[5];
    const float* b2 = (const float*)d_in[6];

    float* out        = (float*)d_out;
    float* out_selpos = out + (size_t)M_SEL * C_OUT;
    float* out_batch  = out_selpos + (size_t)M_SEL * 3;

    char* ws = (char*)d_ws;
    size_t off = 0;
    auto alloc = [&](size_t bytes) -> void* {
        void* p = ws + off;
        off = (off + bytes + 255) & ~(size_t)255;
        return p;
    };
    int*   cnt    = (int*)alloc(NCELL * 4);
    int*   cstart = (int*)alloc((NCELL + 1) * 4);
    int*   cfill  = (int*)alloc(NCELL * 4);
    float* sxp    = (float*)alloc(N_PTS * 4);
    float* syp    = (float*)alloc(N_PTS * 4);
    float* szp    = (float*)alloc(N_PTS * 4);
    int*   orig   = (int*)alloc(N_PTS * 4);
    float* mind   = (float*)alloc(N_PTS * 4);
    int*   sel    = (int*)alloc(M_SEL * 4);
    int*   nbr    = (int*)alloc((size_t)M_SEL * K_NBR * 4);
    int*   ncnt   = (int*)alloc(M_SEL * 4);
    (void)ws_size; (void)in_sizes; (void)n_in; (void)out_size;

    (void)hipMemsetAsync(cnt, 0, NCELL * 4, stream);
    bin_count_kernel<<<N_PTS / 256, 256, 0, stream>>>(pos, cnt);
    scan_kernel<<<1, NCELL, 0, stream>>>(cnt, cstart, cfill);
    scatter_kernel<<<N_PTS / 256, 256, 0, stream>>>(pos, cfill, sxp, syp, szp, orig);
    fps_kernel<<<1, 1024, 0, stream>>>(pos, sxp, syp, szp, orig, cstart, mind, sel);
    ballq_kernel<<<M_SEL / 4, 256, 0, stream>>>(pos, sxp, syp, szp, orig, cstart, sel, nbr, ncnt);
    mlp_kernel<<<M_SEL, 256, 0, stream>>>(x, pos, W1, b1, W2, b2, sel, nbr, ncnt, out);
    tail_kernel<<<(M_SEL + 255) / 256, 256, 0, stream>>>(pos, sel, out_selpos, out_batch);
}